// Round 6
// baseline (426.491 us; speedup 1.0000x reference)
//
#include <hip/hip_runtime.h>

// TemporalXORReservoirNetwork — R6: best-of (R1 occupancy + R2 barrier-free + nt).
//
// R5 post-mortem: corrected graph accounting — harness reset = ws fill
// (1.678 GB, ~268 us) + out fill (419 MB, ~67 us, serial) + W restore
// (~5 us). True kernel times: R1~68us, R2~84, R5~79 => the single-kernel
// variants were already near the 419 MB / 6.3 TB/s = 67 us write floor.
// Differences tracked waves/CU: R1's 1024-thr (16 waves) beat 512-thr
// (8 waves) by ~10 us. R6 = 256 blocks x 1024 thr, 2 neurons/thread,
// barrier-free fast path, nontemporal float2 stores, count-branch peeled
// out of the main 190 steps. Predicted bench ~405-412 us == structural
// floor (can't touch the ~342 us of harness resets).

#define SEQ    200
#define BATCH  256
#define NRES   2048
#define NTHR   1024         // 16 waves/CU — measured best (R1)
#define BETA_F 0.9f

typedef float f2_t __attribute__((ext_vector_type(2)));  // native vec: nt-store OK

__global__ __launch_bounds__(NTHR, 1) void snn_reservoir_kernel(
    const float* __restrict__ x,     // [200, 256, 3]
    const float* __restrict__ W,     // [2048, 2048]  (row k -> col n)
    const float* __restrict__ Win,   // [2048, 3]
    const float* __restrict__ Wout,  // [2, 2048]
    float* __restrict__ out)         // spk_rec [200,256,2048] then logits [256,2]
{
    const int b    = blockIdx.x;
    const int tid  = threadIdx.x;
    const int lane = tid & 63;
    const int wid  = tid >> 6;        // 0..15
    const int n0   = tid << 1;        // neurons n0, n0+1

    __shared__ float4 sx[SEQ];                    // x[:, b, :]
    __shared__ unsigned long long smask[2][32];   // slow path: spike bitmask
    __shared__ int   scum[2];                     // slow path: cumulative spike count
    __shared__ float red[2][16];
    __shared__ int   anyflag;

    for (int t = tid; t < SEQ; t += NTHR) {
        const float* p = x + (size_t)t * (BATCH * 3) + b * 3;
        sx[t] = make_float4(p[0], p[1], p[2], 0.0f);
    }
    if (tid == 0) anyflag = 0;

    // Input weights for 2 neurons (6 floats, done once — scalar loads fine)
    const float* wr = Win + (size_t)n0 * 3;
    const float w00 = wr[0], w01 = wr[1], w02 = wr[2];
    const float w10 = wr[3], w11 = wr[4], w12 = wr[5];

    float V0 = 0.f, V1 = 0.f;
    int cnt0 = 0, cnt1 = 0;

    __syncthreads();   // staging + anyflag visible

    // ---------------- FAST PATH: uncoupled, barrier-free, nt stores ----------------
    {
        float* po = out + (size_t)b * NRES + n0;
        bool spiked = false;
        #pragma unroll 4
        for (int t = 0; t < SEQ - 10; ++t) {
            const float4 xv = sx[t];
            V0 = fmaf(BETA_F, V0, fmaf(xv.x, w00, fmaf(xv.y, w01, xv.z * w02)));
            V1 = fmaf(BETA_F, V1, fmaf(xv.x, w10, fmaf(xv.y, w11, xv.z * w12)));
            const bool s0 = (V0 >= 1.0f), s1 = (V1 >= 1.0f);
            spiked |= (s0 | s1);
            V0 = s0 ? 0.f : V0;
            V1 = s1 ? 0.f : V1;
            f2_t sp; sp[0] = s0 ? 1.f : 0.f; sp[1] = s1 ? 1.f : 0.f;
            __builtin_nontemporal_store(sp, (f2_t*)po);
            po += BATCH * NRES;
        }
        #pragma unroll
        for (int t = SEQ - 10; t < SEQ; ++t) {    // peeled: spike counting
            const float4 xv = sx[t];
            V0 = fmaf(BETA_F, V0, fmaf(xv.x, w00, fmaf(xv.y, w01, xv.z * w02)));
            V1 = fmaf(BETA_F, V1, fmaf(xv.x, w10, fmaf(xv.y, w11, xv.z * w12)));
            const bool s0 = (V0 >= 1.0f), s1 = (V1 >= 1.0f);
            spiked |= (s0 | s1);
            cnt0 += (int)s0; cnt1 += (int)s1;
            V0 = s0 ? 0.f : V0;
            V1 = s1 ? 0.f : V1;
            f2_t sp; sp[0] = s0 ? 1.f : 0.f; sp[1] = s1 ? 1.f : 0.f;
            __builtin_nontemporal_store(sp, (f2_t*)po);
            po += BATCH * NRES;
        }
        const unsigned long long bal = __ballot(spiked);
        if (lane == 0 && bal != 0ull) atomicOr(&anyflag, 1);
    }
    __syncthreads();

    // ---------------- SLOW PATH: coupled re-run (never taken) ----------------
    if (anyflag) {
        V0 = 0.f; V1 = 0.f; cnt0 = 0; cnt1 = 0;
        if (tid < 64) smask[tid >> 5][tid & 31] = 0ull;
        if (tid < 2)  scum[tid] = 0;
        __syncthreads();

        int seen[2] = {0, 0};
        float* po = out + (size_t)b * NRES + n0;
        for (int t = 0; t < SEQ; ++t) {
            const int curp = t & 1, prev = curp ^ 1;
            float rec0 = 0.f, rec1 = 0.f;
            const int c = scum[prev];
            if (c != seen[prev]) {            // spikes at step t-1: gather W rows
                seen[prev] = c;
                // bit l of word 2w   -> n = 128*w + 2*l   (even neurons)
                // bit l of word 2w+1 -> n = 128*w + 2*l+1 (odd neurons)
                #pragma unroll 1
                for (int u = 0; u < 32; ++u) {
                    unsigned long long m = smask[prev][u];
                    const int kbase = ((u >> 1) << 7) + (u & 1);
                    while (m) {
                        const int l = __builtin_ctzll(m);
                        m &= m - 1;
                        const int k = kbase + (l << 1);
                        const float2 wv = *(const float2*)(W + (size_t)k * NRES + n0);
                        rec0 += wv.x; rec1 += wv.y;
                    }
                }
            }
            const float4 xv = sx[t];
            V0 = fmaf(BETA_F, V0, fmaf(xv.x, w00, fmaf(xv.y, w01, xv.z * w02)) + rec0);
            V1 = fmaf(BETA_F, V1, fmaf(xv.x, w10, fmaf(xv.y, w11, xv.z * w12)) + rec1);
            const bool s0 = (V0 >= 1.0f), s1 = (V1 >= 1.0f);
            V0 = s0 ? 0.f : V0;
            V1 = s1 ? 0.f : V1;
            *(float2*)po = make_float2(s0 ? 1.f : 0.f, s1 ? 1.f : 0.f);
            po += BATCH * NRES;
            if (t >= SEQ - 10) { cnt0 += (int)s0; cnt1 += (int)s1; }
            const unsigned long long b0 = __ballot(s0);
            const unsigned long long b1 = __ballot(s1);
            if (lane == 0) {
                smask[curp][2 * wid]     = b0;
                smask[curp][2 * wid + 1] = b1;
                const int pc = __popcll(b0) + __popcll(b1);
                if (pc) atomicAdd(&scum[curp], pc);
            }
            __syncthreads();
        }
    }

    // ---------------- logits epilogue ----------------
    const float a0 = (float)cnt0 * 0.1f;
    const float a1 = (float)cnt1 * 0.1f;
    float p0 = fmaf(a0, Wout[n0], a1 * Wout[n0 + 1]);
    float p1 = fmaf(a0, Wout[NRES + n0], a1 * Wout[NRES + n0 + 1]);
    #pragma unroll
    for (int off = 32; off > 0; off >>= 1) {
        p0 += __shfl_down(p0, off);
        p1 += __shfl_down(p1, off);
    }
    if (lane == 0) { red[0][wid] = p0; red[1][wid] = p1; }
    __syncthreads();
    if (tid == 0) {
        float q0 = 0.f, q1 = 0.f;
        #pragma unroll
        for (int i = 0; i < 16; ++i) { q0 += red[0][i]; q1 += red[1][i]; }
        const size_t loff = (size_t)SEQ * BATCH * NRES;
        out[loff + b * 2 + 0] = q0;
        out[loff + b * 2 + 1] = q1;
    }
}

extern "C" void kernel_launch(void* const* d_in, const int* in_sizes, int n_in,
                              void* d_out, int out_size, void* d_ws, size_t ws_size,
                              hipStream_t stream) {
    const float* x    = (const float*)d_in[0];
    const float* W    = (const float*)d_in[1];
    const float* Win  = (const float*)d_in[2];
    const float* Wout = (const float*)d_in[3];
    float* out = (float*)d_out;
    hipLaunchKernelGGL(snn_reservoir_kernel, dim3(BATCH), dim3(NTHR), 0, stream,
                       x, W, Win, Wout, out);
}